// Round 7
// baseline (113.209 us; speedup 1.0000x reference)
//
#include <hip/hip_runtime.h>
#include <hip/hip_cooperative_groups.h>

namespace cg = cooperative_groups;

#define IMG_H 720
#define IMG_W 1280
#define NPIX (IMG_H * IMG_W)
#define FX_C 800.0f
#define FY_C 800.0f
#define CX_C 640.0f
#define CY_C 360.0f

// Hot window around the projection center (640, 360).
// sigma_u = sigma_v ~= 11.4 px; +/-48 px ~= +/-4.2 sigma. Out-of-window points
// (~200 expected) take a test-and-skip global-atomic path, so correctness does
// NOT depend on the distribution.
#define WIN_W 96
#define WIN_H 96
#define WIN_X0 (640 - WIN_W / 2)  // 592
#define WIN_Y0 (360 - WIN_H / 2)  // 312
#define WIN_PIX (WIN_W * WIN_H)   // 9216
#define LDS_STRIDE 97             // pad: bank index must not be f(wx) only

#define NBLK 256                  // one block per CU
#define NTHR 1024                 // 16 waves/CU
#define NR 16                     // first-stage reduction groups (256 -> 16)

__device__ __forceinline__ void project_point(float x, float y, float zraw,
                                              float& u, float& v) {
    float z = __fadd_rn(zraw, 3.0f);
    // IEEE-exact, no FMA contraction: must bit-match numpy so floor() agrees
    u = __fadd_rn(__fmul_rn(FX_C, __fdiv_rn(x, z)), CX_C);
    v = __fadd_rn(__fmul_rn(FY_C, __fdiv_rn(y, z)), CY_C);
}

__device__ __forceinline__ void splat_one(int i, float x, float y, float zraw,
                                          int* lwin, int* __restrict__ winner) {
    float u, v;
    project_point(x, y, zraw, u, v);
    if (u >= 0.0f && u < (float)IMG_W && v >= 0.0f && v < (float)IMG_H) {
        int xi = (int)floorf(u);
        int yi = (int)floorf(v);
        int wx = xi - WIN_X0;
        int wy = yi - WIN_Y0;
        if ((unsigned)wx < WIN_W && (unsigned)wy < WIN_H) {
            atomicMax(&lwin[wy * LDS_STRIDE + wx], i);     // CU-local, no coherence
        } else {
            int pix = yi * IMG_W + xi;                     // rare fallback
            if (winner[pix] < i) atomicMax(&winner[pix], i);
        }
    }
}

__global__ __launch_bounds__(NTHR) void fused_kernel(
        const float* __restrict__ pos, const float* __restrict__ scales,
        const float* __restrict__ colors, int* __restrict__ winner,
        int* __restrict__ blockwin, int* __restrict__ part16,
        float* __restrict__ out, int n, int per_block) {
    cg::grid_group grid = cg::this_grid();
    __shared__ int lwin[WIN_H * LDS_STRIDE];

    const int tid = blockIdx.x * NTHR + (int)threadIdx.x;
    const int nthreads = NBLK * NTHR;

    // ---- Phase 0: winner = -1 (int4 stores), lwin = -1 ----
    int4* w4 = (int4*)winner;
    for (int i = tid; i < NPIX / 4; i += nthreads)
        w4[i] = make_int4(-1, -1, -1, -1);
    for (int j = threadIdx.x; j < WIN_H * LDS_STRIDE; j += NTHR)
        lwin[j] = -1;
    grid.sync();  // winner init visible device-wide before any fallback atomic

    // ---- Phase 1: scatter into LDS window (+ rare global fallback) ----
    int base = blockIdx.x * per_block;
    int end  = base + per_block;
    if (end > n) end = n;

    for (int i0 = base + (int)threadIdx.x * 4; i0 < end; i0 += NTHR * 4) {
        if (i0 + 4 <= end) {
            // 4 points = 48 contiguous bytes = 3 x float4 (16B-aligned since i0%4==0)
            const float4* p4 = (const float4*)(pos + 3 * i0);
            float4 a = p4[0], b = p4[1], c = p4[2];
            splat_one(i0 + 0, a.x, a.y, a.z, lwin, winner);
            splat_one(i0 + 1, a.w, b.x, b.y, lwin, winner);
            splat_one(i0 + 2, b.z, b.w, c.x, lwin, winner);
            splat_one(i0 + 3, c.y, c.z, c.w, lwin, winner);
        } else {
            for (int i = i0; i < end; ++i)
                splat_one(i, pos[3 * i], pos[3 * i + 1], pos[3 * i + 2], lwin, winner);
        }
    }
    __syncthreads();

    // flush LDS window to PRIVATE global slice (coalesced, no sharing)
    {
        int* dst = blockwin + (size_t)blockIdx.x * WIN_PIX;
        for (int j = threadIdx.x; j < WIN_PIX; j += NTHR) {
            int wy = j / WIN_W;
            int wx = j - wy * WIN_W;
            dst[j] = lwin[wy * LDS_STRIDE + wx];
        }
    }
    grid.sync();

    // ---- Phase 2: reduce 256 block windows -> NR partials ----
    for (int t = tid; t < NR * WIN_PIX; t += nthreads) {
        int g = t / WIN_PIX;
        int p = t - g * WIN_PIX;
        const int* src = blockwin + (size_t)(g * (NBLK / NR)) * WIN_PIX + p;
        int m = -1;
        #pragma unroll
        for (int b = 0; b < NBLK / NR; ++b) {
            int v = src[(size_t)b * WIN_PIX];
            m = v > m ? v : m;
        }
        part16[t] = m;
    }
    grid.sync();

    // ---- Phase 3: resolve ----
    for (int p = tid; p < NPIX; p += nthreads) {
        int py = p / IMG_W;
        int px = p - py * IMG_W;
        int wx = px - WIN_X0;
        int wy = py - WIN_Y0;
        int w;
        if ((unsigned)wx < WIN_W && (unsigned)wy < WIN_H) {
            int wp = wy * WIN_W + wx;
            int m = -1;
            #pragma unroll
            for (int g = 0; g < NR; ++g) {
                int v = part16[g * WIN_PIX + wp];
                m = v > m ? v : m;
            }
            w = m;
        } else {
            w = winner[p];
        }
        float cr = 0.0f, cgr = 0.0f, cb = 0.0f;
        if (w >= 0) {
            float u, v;
            project_point(pos[3 * w], pos[3 * w + 1], pos[3 * w + 2], u, v);
            float dx = __fsub_rn(u, floorf(u));
            float dy = __fsub_rn(v, floorf(v));
            float rad = __fmul_rn(scales[3 * w], 100.0f);
            float num = __fadd_rn(__fmul_rn(dx, dx), __fmul_rn(dy, dy));
            float den = __fmul_rn(2.0f, __fmul_rn(rad, rad));
            float wgt = expf(-__fdiv_rn(num, den));
            cr  = __fmul_rn(colors[3 * w + 0], wgt);
            cgr = __fmul_rn(colors[3 * w + 1], wgt);
            cb  = __fmul_rn(colors[3 * w + 2], wgt);
        }
        out[3 * p + 0] = cr;
        out[3 * p + 1] = cgr;
        out[3 * p + 2] = cb;
    }
}

// ---------- fallback path (ws too small): simple 3-kernel version ----------
__global__ __launch_bounds__(256) void init_winner_kernel(int4* __restrict__ winner4,
                                                          int nquads) {
    int stride = gridDim.x * blockDim.x;
    for (int i = blockIdx.x * blockDim.x + threadIdx.x; i < nquads; i += stride)
        winner4[i] = make_int4(-1, -1, -1, -1);
}

__global__ void scatter_simple_kernel(const float* __restrict__ pos,
                                      int* __restrict__ winner, int n) {
    int gid = blockIdx.x * blockDim.x + threadIdx.x;
    if (gid >= n) return;
    int i = n - 1 - gid;
    float u, v;
    project_point(pos[3 * i], pos[3 * i + 1], pos[3 * i + 2], u, v);
    if (u >= 0.0f && u < (float)IMG_W && v >= 0.0f && v < (float)IMG_H) {
        int pix = (int)floorf(v) * IMG_W + (int)floorf(u);
        if (winner[pix] < i) atomicMax(&winner[pix], i);
    }
}

__global__ __launch_bounds__(256) void resolve_simple_kernel(
        const float* __restrict__ pos, const float* __restrict__ scales,
        const float* __restrict__ colors, const int* __restrict__ winner,
        float* __restrict__ out, int npix) {
    int p = blockIdx.x * blockDim.x + threadIdx.x;
    if (p >= npix) return;
    int w = winner[p];
    float cr = 0.0f, cgr = 0.0f, cb = 0.0f;
    if (w >= 0) {
        float u, v;
        project_point(pos[3 * w], pos[3 * w + 1], pos[3 * w + 2], u, v);
        float dx = __fsub_rn(u, floorf(u));
        float dy = __fsub_rn(v, floorf(v));
        float rad = __fmul_rn(scales[3 * w], 100.0f);
        float num = __fadd_rn(__fmul_rn(dx, dx), __fmul_rn(dy, dy));
        float den = __fmul_rn(2.0f, __fmul_rn(rad, rad));
        float wgt = expf(-__fdiv_rn(num, den));
        cr  = __fmul_rn(colors[3 * w + 0], wgt);
        cgr = __fmul_rn(colors[3 * w + 1], wgt);
        cb  = __fmul_rn(colors[3 * w + 2], wgt);
    }
    out[3 * p + 0] = cr;
    out[3 * p + 1] = cgr;
    out[3 * p + 2] = cb;
}

extern "C" void kernel_launch(void* const* d_in, const int* in_sizes, int n_in,
                              void* d_out, int out_size, void* d_ws, size_t ws_size,
                              hipStream_t stream) {
    // inputs: [0] camera_poses (unused), [1] positions, [2] scales, [3] colors
    const float* positions = (const float*)d_in[1];
    const float* scales    = (const float*)d_in[2];
    const float* colors    = (const float*)d_in[3];
    float* out = (float*)d_out;
    int n = in_sizes[1] / 3;

    const size_t winner_bytes   = (size_t)NPIX * sizeof(int);
    const size_t part16_bytes   = (size_t)NR * WIN_PIX * sizeof(int);
    const size_t blockwin_bytes = (size_t)NBLK * WIN_PIX * sizeof(int);

    int* winner = (int*)d_ws;

    if (ws_size >= winner_bytes + part16_bytes + blockwin_bytes) {
        int* part16   = (int*)((char*)d_ws + winner_bytes);
        int* blockwin = (int*)((char*)d_ws + winner_bytes + part16_bytes);
        int per_block = ((n + NBLK - 1) / NBLK + 3) & ~3;  // multiple of 4

        void* args[] = { (void*)&positions, (void*)&scales, (void*)&colors,
                         (void*)&winner, (void*)&blockwin, (void*)&part16,
                         (void*)&out, (void*)&n, (void*)&per_block };
        hipLaunchCooperativeKernel((const void*)fused_kernel,
                                   dim3(NBLK), dim3(NTHR), args, 0, stream);
    } else {
        init_winner_kernel<<<900, 256, 0, stream>>>((int4*)winner, NPIX / 4);
        scatter_simple_kernel<<<(n + 255) / 256, 256, 0, stream>>>(positions, winner, n);
        resolve_simple_kernel<<<(NPIX + 255) / 256, 256, 0, stream>>>(
            positions, scales, colors, winner, out, NPIX);
    }
}

// Round 8
// 37.674 us; speedup vs baseline: 3.0049x; 3.0049x over previous
//
#include <hip/hip_runtime.h>

#define IMG_H 720
#define IMG_W 1280
#define NPIX (IMG_H * IMG_W)
#define FX_C 800.0f
#define FY_C 800.0f
#define CX_C 640.0f
#define CY_C 360.0f

// Hot window around the projection center (640, 360).
// sigma_u = sigma_v ~= 11.4 px; +/-48 px ~= +/-4.2 sigma. Out-of-window points
// (~200 expected) take a test-and-skip global-atomic path, so correctness does
// NOT depend on the distribution.
#define WIN_W 96
#define WIN_H 96
#define WIN_X0 (640 - WIN_W / 2)  // 592
#define WIN_Y0 (360 - WIN_H / 2)  // 312
#define WIN_PIX (WIN_W * WIN_H)   // 9216
#define LDS_STRIDE 97             // pad: bank index must not be f(wx) only

#define SCAT_BLOCKS 256           // one block per CU
#define SCAT_THREADS 512          // 8 waves/CU
#define RBLK 36                   // dedicated window-reducer blocks in resolve
// NOTE (round 7 lesson): cooperative grid.sync() costs ~30us EACH on MI355X
// (cross-XCD coherence spin) — 3-kernel stream ordering is far cheaper.

// K0: winner = -1 via int4 grid-stride (rocclr fillBuffer kernel is ~40us-slow)
__global__ __launch_bounds__(256) void init_winner_kernel(int4* __restrict__ winner4,
                                                          int nquads) {
    int i = blockIdx.x * blockDim.x + threadIdx.x;
    if (i < nquads) winner4[i] = make_int4(-1, -1, -1, -1);
}

__device__ __forceinline__ void project_point(float x, float y, float zraw,
                                              float& u, float& v) {
    float z = __fadd_rn(zraw, 3.0f);
    // IEEE-exact, no FMA contraction: must bit-match numpy so floor() agrees
    u = __fadd_rn(__fmul_rn(FX_C, __fdiv_rn(x, z)), CX_C);
    v = __fadd_rn(__fmul_rn(FY_C, __fdiv_rn(y, z)), CY_C);
}

__device__ __forceinline__ void splat_one(int i, float x, float y, float zraw,
                                          int* lwin, int* __restrict__ winner) {
    float u, v;
    project_point(x, y, zraw, u, v);
    if (u >= 0.0f && u < (float)IMG_W && v >= 0.0f && v < (float)IMG_H) {
        int xi = (int)floorf(u);
        int yi = (int)floorf(v);
        int wx = xi - WIN_X0;
        int wy = yi - WIN_Y0;
        if ((unsigned)wx < WIN_W && (unsigned)wy < WIN_H) {
            atomicMax(&lwin[wy * LDS_STRIDE + wx], i);     // CU-local, no coherence
        } else {
            int pix = yi * IMG_W + xi;                     // rare fallback
            if (winner[pix] < i) atomicMax(&winner[pix], i);
        }
    }
}

// K1: LDS-privatized window scatter, flushed to a PRIVATE global slice.
__global__ __launch_bounds__(SCAT_THREADS) void scatter_win_kernel(
        const float* __restrict__ pos, int* __restrict__ winner,
        int* __restrict__ blockwin, int n, int per_block) {
    __shared__ int lwin[WIN_H * LDS_STRIDE];
    for (int j = threadIdx.x; j < WIN_H * LDS_STRIDE; j += SCAT_THREADS) lwin[j] = -1;
    __syncthreads();

    int base = blockIdx.x * per_block;
    int end  = base + per_block;
    if (end > n) end = n;

    #pragma unroll 2
    for (int i0 = base + (int)threadIdx.x * 4; i0 < end; i0 += SCAT_THREADS * 4) {
        if (i0 + 4 <= end) {
            // 4 points = 48 contiguous bytes = 3 x float4 (16B-aligned since i0%4==0)
            const float4* p4 = (const float4*)(pos + 3 * i0);
            float4 a = p4[0], b = p4[1], c = p4[2];
            splat_one(i0 + 0, a.x, a.y, a.z, lwin, winner);
            splat_one(i0 + 1, a.w, b.x, b.y, lwin, winner);
            splat_one(i0 + 2, b.z, b.w, c.x, lwin, winner);
            splat_one(i0 + 3, c.y, c.z, c.w, lwin, winner);
        } else {
            for (int i = i0; i < end; ++i)
                splat_one(i, pos[3 * i], pos[3 * i + 1], pos[3 * i + 2], lwin, winner);
        }
    }
    __syncthreads();

    int* dst = blockwin + (size_t)blockIdx.x * WIN_PIX;
    for (int j = threadIdx.x; j < WIN_PIX; j += SCAT_THREADS) {
        int wy = j / WIN_W;
        int wx = j - wy * WIN_W;
        dst[j] = lwin[wy * LDS_STRIDE + wx];    // coalesced private store
    }
}

__device__ __forceinline__ void shade_and_store(
        const float* __restrict__ pos, const float* __restrict__ scales,
        const float* __restrict__ colors, float* __restrict__ out, int p, int w) {
    float cr = 0.0f, cgr = 0.0f, cb = 0.0f;
    if (w >= 0) {
        float u, v;
        project_point(pos[3 * w], pos[3 * w + 1], pos[3 * w + 2], u, v);
        float dx = __fsub_rn(u, floorf(u));
        float dy = __fsub_rn(v, floorf(v));
        float rad = __fmul_rn(scales[3 * w], 100.0f);
        float num = __fadd_rn(__fmul_rn(dx, dx), __fmul_rn(dy, dy));
        float den = __fmul_rn(2.0f, __fmul_rn(rad, rad));
        float wgt = expf(-__fdiv_rn(num, den));
        cr  = __fmul_rn(colors[3 * w + 0], wgt);
        cgr = __fmul_rn(colors[3 * w + 1], wgt);
        cb  = __fmul_rn(colors[3 * w + 2], wgt);
    }
    out[3 * p + 0] = cr;
    out[3 * p + 1] = cgr;
    out[3 * p + 2] = cb;
}

// K2: resolve. Blocks [0,RBLK): one thread per window pixel, reduce 256
// blockwin slices (4 independent max chains for ILP), shade, store.
// Blocks [RBLK, ...): normal pixels from winner[]; window pixels skipped.
__global__ __launch_bounds__(256) void resolve_kernel(
        const float* __restrict__ pos, const float* __restrict__ scales,
        const float* __restrict__ colors, const int* __restrict__ blockwin,
        const int* __restrict__ winner, float* __restrict__ out,
        int npix, int nblocks_scat, int use_blockwin) {
    if (use_blockwin && blockIdx.x < RBLK) {
        int wp = blockIdx.x * 256 + threadIdx.x;   // RBLK*256 == WIN_PIX
        const int* src = blockwin + wp;
        int m0 = -1, m1 = -1, m2 = -1, m3 = -1;
        int b = 0;
        for (; b + 4 <= nblocks_scat; b += 4) {
            int v0 = src[(size_t)(b + 0) * WIN_PIX];
            int v1 = src[(size_t)(b + 1) * WIN_PIX];
            int v2 = src[(size_t)(b + 2) * WIN_PIX];
            int v3 = src[(size_t)(b + 3) * WIN_PIX];
            m0 = v0 > m0 ? v0 : m0;
            m1 = v1 > m1 ? v1 : m1;
            m2 = v2 > m2 ? v2 : m2;
            m3 = v3 > m3 ? v3 : m3;
        }
        for (; b < nblocks_scat; ++b) {
            int v = src[(size_t)b * WIN_PIX];
            m0 = v > m0 ? v : m0;
        }
        int m = m0 > m1 ? m0 : m1;
        int mb = m2 > m3 ? m2 : m3;
        m = m > mb ? m : mb;
        int wy = wp / WIN_W;
        int wx = wp - wy * WIN_W;
        int p = (WIN_Y0 + wy) * IMG_W + (WIN_X0 + wx);
        shade_and_store(pos, scales, colors, out, p, m);
        return;
    }
    int p = (blockIdx.x - (use_blockwin ? RBLK : 0)) * 256 + (int)threadIdx.x;
    if (p >= npix) return;
    if (use_blockwin) {
        int py = p / IMG_W;
        int px = p - py * IMG_W;
        if ((unsigned)(px - WIN_X0) < WIN_W && (unsigned)(py - WIN_Y0) < WIN_H)
            return;  // handled by reducer blocks
    }
    shade_and_store(pos, scales, colors, out, p, winner[p]);
}

// Fallback scatter (round-2 style) if workspace is too small for blockwin.
__global__ void scatter_simple_kernel(const float* __restrict__ pos,
                                      int* __restrict__ winner, int n) {
    int gid = blockIdx.x * blockDim.x + threadIdx.x;
    if (gid >= n) return;
    int i = n - 1 - gid;
    float u, v;
    project_point(pos[3 * i], pos[3 * i + 1], pos[3 * i + 2], u, v);
    if (u >= 0.0f && u < (float)IMG_W && v >= 0.0f && v < (float)IMG_H) {
        int pix = (int)floorf(v) * IMG_W + (int)floorf(u);
        if (winner[pix] < i) atomicMax(&winner[pix], i);
    }
}

extern "C" void kernel_launch(void* const* d_in, const int* in_sizes, int n_in,
                              void* d_out, int out_size, void* d_ws, size_t ws_size,
                              hipStream_t stream) {
    // inputs: [0] camera_poses (unused), [1] positions, [2] scales, [3] colors
    const float* positions = (const float*)d_in[1];
    const float* scales    = (const float*)d_in[2];
    const float* colors    = (const float*)d_in[3];
    float* out = (float*)d_out;
    int n = in_sizes[1] / 3;

    const size_t winner_bytes   = (size_t)NPIX * sizeof(int);
    const size_t blockwin_bytes = (size_t)SCAT_BLOCKS * WIN_PIX * sizeof(int);

    int* winner = (int*)d_ws;

    // K0: init winner (921600 ints = 230400 int4)
    init_winner_kernel<<<NPIX / 4 / 256, 256, 0, stream>>>((int4*)winner, NPIX / 4);

    if (ws_size >= winner_bytes + blockwin_bytes) {
        int* blockwin = (int*)((char*)d_ws + winner_bytes);
        int per_block = ((n + SCAT_BLOCKS - 1) / SCAT_BLOCKS + 3) & ~3;  // mult of 4

        scatter_win_kernel<<<SCAT_BLOCKS, SCAT_THREADS, 0, stream>>>(
            positions, winner, blockwin, n, per_block);
        resolve_kernel<<<RBLK + (NPIX + 255) / 256, 256, 0, stream>>>(
            positions, scales, colors, blockwin, winner, out, NPIX, SCAT_BLOCKS, 1);
    } else {
        scatter_simple_kernel<<<(n + 255) / 256, 256, 0, stream>>>(positions, winner, n);
        resolve_kernel<<<(NPIX + 255) / 256, 256, 0, stream>>>(
            positions, scales, colors, (const int*)winner /*unused*/, winner, out,
            NPIX, 0, 0);
    }
}